// Round 2
// baseline (17715.739 us; speedup 1.0000x reference)
//
#include <hip/hip_runtime.h>
#include <hip/hip_bf16.h>

typedef _Float16 half4v __attribute__((ext_vector_type(4)));
typedef _Float16 half8v __attribute__((ext_vector_type(8)));
typedef float f32x4 __attribute__((ext_vector_type(4)));

#define T_STEPS 256
#define BATCH 64
#define NHID 512
#define NINP 512
#define MROWS (T_STEPS * BATCH)          // 16384
#define KDIM (2 * NINP)                  // 1024
#define NOUT (2 * NHID + NHID)           // 1536

// ---------------------------------------------------------------- converts

__global__ __launch_bounds__(256) void k_convert_x(
    const float* __restrict__ inp, const float* __restrict__ sem,
    _Float16* __restrict__ xh) {
  int idx = blockIdx.x * 256 + threadIdx.x;
  const int G = MROWS * KDIM / 4;
  for (int g = idx; g < G; g += 2048 * 256) {
    int e = g * 4;
    int m = e >> 10, k = e & 1023;
    const float* src = (k < NINP) ? (inp + (size_t)m * NINP + k)
                                  : (sem + (size_t)m * NINP + (k - NINP));
    float4 v = *(const float4*)src;
    half4v o = { (_Float16)v.x, (_Float16)v.y, (_Float16)v.z, (_Float16)v.w };
    *(half4v*)(xh + (size_t)e) = o;
  }
}

__global__ __launch_bounds__(256) void k_convert_w(
    const float* __restrict__ W_ioux, const float* __restrict__ W_fx,
    const float* __restrict__ b_ioux, const float* __restrict__ b_fx,
    _Float16* __restrict__ wbig, float* __restrict__ biasN) {
  int g = blockIdx.x * 256 + threadIdx.x;
  int e = g * 4;
  int n = e >> 10, k = e & 1023;
  const float* src = (n < 2 * NHID) ? (W_ioux + (size_t)n * KDIM + k)
                                    : (W_fx + (size_t)(n - 2 * NHID) * KDIM + k);
  float4 v = *(const float4*)src;
  half4v o = { (_Float16)v.x, (_Float16)v.y, (_Float16)v.z, (_Float16)v.w };
  *(half4v*)(wbig + (size_t)e) = o;
  if (g < NOUT) biasN[g] = (g < 2 * NHID) ? b_ioux[g] : b_fx[g - 2 * NHID];
}

__global__ __launch_bounds__(256) void k_convert_wrec(
    const float* __restrict__ W_iouh, const float* __restrict__ W_Uh,
    _Float16* __restrict__ wrec) {
  int g = blockIdx.x * 256 + threadIdx.x;
  int e = g * 4;
  const int NI = 2 * NHID * NHID;
  const float* src = (e < NI) ? (W_iouh + e) : (W_Uh + (e - NI));
  float4 v = *(const float4*)src;
  half4v o = { (_Float16)v.x, (_Float16)v.y, (_Float16)v.z, (_Float16)v.w };
  *(half4v*)(wrec + (size_t)e) = o;
}

// ---------------------------------------------------------------- GEMM

__device__ __forceinline__ void gload16(const void* g, void* l) {
  __builtin_amdgcn_global_load_lds(
      (const __attribute__((address_space(1))) unsigned int*)g,
      (__attribute__((address_space(3))) unsigned int*)l, 16, 0, 0);
}

__global__ __launch_bounds__(256) void gemm_bt(
    const _Float16* __restrict__ A, const _Float16* __restrict__ Bm,
    const float* __restrict__ biasN, float* __restrict__ C,
    int M, int N, int K) {
  __shared__ __align__(16) _Float16 As[128 * 32];
  __shared__ __align__(16) _Float16 Bs[128 * 32];
  const int tid = threadIdx.x;
  const int lane = tid & 63;
  const int w = tid >> 6;
  const int wr = w >> 1, wc = w & 1;
  const int nbm = M >> 7;
  const int bm = blockIdx.x % nbm, bn = blockIdx.x / nbm;
  const int m0 = bm << 7, n0 = bn << 7;
  const int lr = lane & 15, lh = lane >> 4;

  f32x4 acc[4][4] = {};

  for (int kk = 0; kk < K; kk += 32) {
#pragma unroll
    for (int c = 0; c < 2; ++c) {
      int L = (c * 256 + tid) * 16;
      int row = L >> 6, inrow = L & 63;
      gload16((const char*)A + ((size_t)(m0 + row) * K + kk) * 2 + inrow,
              (char*)As + L);
      gload16((const char*)Bm + ((size_t)(n0 + row) * K + kk) * 2 + inrow,
              (char*)Bs + L);
    }
    __syncthreads();
    half8v af[4], bf[4];
#pragma unroll
    for (int i = 0; i < 4; ++i)
      af[i] = *(const half8v*)&As[(wr * 64 + i * 16 + lr) * 32 + lh * 8];
#pragma unroll
    for (int i = 0; i < 4; ++i)
      bf[i] = *(const half8v*)&Bs[(wc * 64 + i * 16 + lr) * 32 + lh * 8];
#pragma unroll
    for (int i = 0; i < 4; ++i)
#pragma unroll
      for (int j = 0; j < 4; ++j)
        acc[i][j] = __builtin_amdgcn_mfma_f32_16x16x32_f16(af[i], bf[j], acc[i][j], 0, 0, 0);
    __syncthreads();
  }

#pragma unroll
  for (int i = 0; i < 4; ++i)
#pragma unroll
    for (int j = 0; j < 4; ++j) {
      int n = n0 + wc * 64 + j * 16 + lr;
      float bv = biasN[n];
#pragma unroll
      for (int q = 0; q < 4; ++q) {
        int m = m0 + wr * 64 + i * 16 + lh * 4 + q;
        C[(size_t)m * N + n] = acc[i][j][q] + bv;
      }
    }
}

// ---------------------------------------------------------------- recurrence
// 4 WGs per chain (bid = g*64 + c -> same XCD per chain, perf heuristic only).
// Each WG owns hidden slice [g*128,(g+1)*128): z-rows, r-rows, Uh-rows.
// Weights live in registers: per thread 3 rows x 128-K-slice = 192 VGPRs.
// Cross-WG exchange: r*h and h (f16, 1KB each) via L2 + threadfence + flags.

__device__ __forceinline__ float dot8(half8v a, half8v b, float acc) {
  acc = __builtin_amdgcn_fdot2(__builtin_shufflevector(a, a, 0, 1),
                               __builtin_shufflevector(b, b, 0, 1), acc, false);
  acc = __builtin_amdgcn_fdot2(__builtin_shufflevector(a, a, 2, 3),
                               __builtin_shufflevector(b, b, 2, 3), acc, false);
  acc = __builtin_amdgcn_fdot2(__builtin_shufflevector(a, a, 4, 5),
                               __builtin_shufflevector(b, b, 4, 5), acc, false);
  acc = __builtin_amdgcn_fdot2(__builtin_shufflevector(a, a, 6, 7),
                               __builtin_shufflevector(b, b, 6, 7), acc, false);
  return acc;
}

__device__ __forceinline__ float sigm(float v) { return 1.f / (1.f + __expf(-v)); }

__global__ __launch_bounds__(512, 2) void recur2(
    const _Float16* __restrict__ Wrec, const float* __restrict__ b_iouh,
    const float* __restrict__ b_Uh, const float* __restrict__ hx,
    const float* __restrict__ proj, _Float16* __restrict__ hbuf,
    _Float16* __restrict__ rhbuf, int* __restrict__ flags,
    float* __restrict__ out) {
  __shared__ __align__(16) _Float16 hh[NHID];
  __shared__ __align__(16) _Float16 rr[NHID];

  const int bid = blockIdx.x;
  const int c = bid & 63, g = bid >> 6;
  const int tid = threadIdx.x;
  const int q = tid & 3, rho = tid >> 2;           // q: K-quarter, rho: row
  const int u = g * 128 + rho;                     // hidden index / Uh row
  const int jz = u, jr = 512 + u;                  // z row, r row
  int* fh = flags + c;
  int* fr = flags + 64 + c;

  const _Float16* Wi = Wrec;
  const _Float16* WU = Wrec + 1024 * 512;

  // pin weights in VGPRs: 48 x half8v = 192 regs
  half8v wz[16], wrg[16], wu[16];
#pragma unroll
  for (int i = 0; i < 16; ++i) {
    wz[i]  = *(const half8v*)(Wi + (size_t)jz * 512 + q * 128 + i * 8);
    wrg[i] = *(const half8v*)(Wi + (size_t)jr * 512 + q * 128 + i * 8);
    wu[i]  = *(const half8v*)(WU + (size_t)u  * 512 + q * 128 + i * 8);
  }

  float bz = 0, br = 0, bu = 0, hmy = 0, zk = 0;
  if (q == 0) {
    bz = b_iouh[jz]; br = b_iouh[jr]; bu = b_Uh[u];
    hmy = hx[(size_t)c * 512 + u];
    hbuf[(size_t)c * 512 + u] = (_Float16)hmy;     // publish h_0 slice
  }
  __syncthreads();        // drains vmcnt -> stores in L2
  __threadfence();
  if (tid == 0) atomicAdd(fh, 1);

  for (int t = 0; t < T_STEPS; ++t) {
    // proj loads are flag-independent: issue early, overlap the spin
    const float* pb = proj + (size_t)(t * BATCH + c) * NOUT;
    float pz = 0, pr = 0, pf = 0;
    if (q == 0) { pz = pb[jz]; pr = pb[jr]; pf = pb[1024 + u]; }

    // ---- wait for h_t (all 4 slices)
    if (tid == 0) {
      while (__hip_atomic_load(fh, __ATOMIC_ACQUIRE, __HIP_MEMORY_SCOPE_AGENT) < 4 * t + 4)
        __builtin_amdgcn_s_sleep(2);
    }
    __syncthreads();
    if (tid < 64) ((int4*)hh)[tid] = ((const int4*)(hbuf + (size_t)c * 512))[tid];
    __syncthreads();

    // ---- phase 1: z, r for my slice
    float za = 0, ra = 0;
    const _Float16* hq = hh + q * 128;
#pragma unroll
    for (int ch = 0; ch < 4; ++ch) {
      half8v h0 = *(const half8v*)(hq + ch * 32);
      half8v h1 = *(const half8v*)(hq + ch * 32 + 8);
      half8v h2 = *(const half8v*)(hq + ch * 32 + 16);
      half8v h3 = *(const half8v*)(hq + ch * 32 + 24);
      za = dot8(wz[ch * 4 + 0], h0, za); za = dot8(wz[ch * 4 + 1], h1, za);
      za = dot8(wz[ch * 4 + 2], h2, za); za = dot8(wz[ch * 4 + 3], h3, za);
      ra = dot8(wrg[ch * 4 + 0], h0, ra); ra = dot8(wrg[ch * 4 + 1], h1, ra);
      ra = dot8(wrg[ch * 4 + 2], h2, ra); ra = dot8(wrg[ch * 4 + 3], h3, ra);
    }
    za += __shfl_xor(za, 1); za += __shfl_xor(za, 2);
    ra += __shfl_xor(ra, 1); ra += __shfl_xor(ra, 2);
    if (q == 0) {
      zk = sigm(za + pz + bz);
      float rv = sigm(ra + pr + br);
      rhbuf[(size_t)c * 512 + u] = (_Float16)(rv * hmy);
    }
    __syncthreads();
    __threadfence();
    if (tid == 0) atomicAdd(fr, 1);

    // ---- wait for full r*h
    if (tid == 0) {
      while (__hip_atomic_load(fr, __ATOMIC_ACQUIRE, __HIP_MEMORY_SCOPE_AGENT) < 4 * t + 4)
        __builtin_amdgcn_s_sleep(2);
    }
    __syncthreads();
    if (tid < 64) ((int4*)rr)[tid] = ((const int4*)(rhbuf + (size_t)c * 512))[tid];
    __syncthreads();

    // ---- phase 2: htilde, h_new for my slice
    float ua = 0;
    const _Float16* rq = rr + q * 128;
#pragma unroll
    for (int ch = 0; ch < 4; ++ch) {
      half8v r0 = *(const half8v*)(rq + ch * 32);
      half8v r1 = *(const half8v*)(rq + ch * 32 + 8);
      half8v r2 = *(const half8v*)(rq + ch * 32 + 16);
      half8v r3 = *(const half8v*)(rq + ch * 32 + 24);
      ua = dot8(wu[ch * 4 + 0], r0, ua); ua = dot8(wu[ch * 4 + 1], r1, ua);
      ua = dot8(wu[ch * 4 + 2], r2, ua); ua = dot8(wu[ch * 4 + 3], r3, ua);
    }
    ua += __shfl_xor(ua, 1); ua += __shfl_xor(ua, 2);
    if (q == 0) {
      float v = ua + pf + bu;
      float e = __expf(-2.f * fabsf(v));
      float th = (1.f - e) / (1.f + e);
      th = (v < 0.f) ? -th : th;
      float hn = fmaf(zk, th - hmy, hmy);
      out[(size_t)(t * BATCH + c) * NHID + u] = hn;
      hmy = hn;
      hbuf[(size_t)c * 512 + u] = (_Float16)hn;
    }
    __syncthreads();
    __threadfence();
    if (tid == 0) atomicAdd(fh, 1);
  }

  if (q == 0)
    out[(size_t)T_STEPS * BATCH * NHID + (size_t)c * NHID + u] = hmy;
}

// ---------------------------------------------------------------- launcher

extern "C" void kernel_launch(void* const* d_in, const int* in_sizes, int n_in,
                              void* d_out, int out_size, void* d_ws, size_t ws_size,
                              hipStream_t stream) {
  const float* inputs = (const float*)d_in[0];
  const float* sememe = (const float*)d_in[1];
  const float* hx     = (const float*)d_in[2];
  const float* W_ioux = (const float*)d_in[3];
  const float* b_ioux = (const float*)d_in[4];
  const float* W_iouh = (const float*)d_in[5];
  const float* b_iouh = (const float*)d_in[6];
  const float* W_fx   = (const float*)d_in[7];
  const float* b_fx   = (const float*)d_in[8];
  const float* W_Uh   = (const float*)d_in[9];
  const float* b_Uh   = (const float*)d_in[10];
  float* out = (float*)d_out;

  char* ws = (char*)d_ws;
  _Float16* xh = (_Float16*)ws;   ws += (size_t)MROWS * KDIM * 2;
  _Float16* wbig = (_Float16*)ws; ws += (size_t)NOUT * KDIM * 2;
  float* biasN = (float*)ws;      ws += (size_t)NOUT * 4;
  _Float16* wrec = (_Float16*)ws; ws += (size_t)(3 * NHID * NHID) * 2;
  float* proj = (float*)ws;       ws += (size_t)MROWS * NOUT * 4;
  _Float16* hbuf = (_Float16*)ws; ws += (size_t)BATCH * NHID * 2;
  _Float16* rhbuf = (_Float16*)ws; ws += (size_t)BATCH * NHID * 2;
  int* flags = (int*)ws;          ws += 128 * 4;

  hipMemsetAsync(flags, 0, 128 * 4, stream);
  k_convert_x<<<2048, 256, 0, stream>>>(inputs, sememe, xh);
  k_convert_w<<<(NOUT * KDIM / 4) / 256, 256, 0, stream>>>(W_ioux, W_fx, b_ioux, b_fx, wbig, biasN);
  k_convert_wrec<<<(3 * NHID * NHID / 4) / 256, 256, 0, stream>>>(W_iouh, W_Uh, wrec);
  gemm_bt<<<(MROWS / 128) * (NOUT / 128), 256, 0, stream>>>(xh, wbig, biasN, proj, MROWS, NOUT, KDIM);
  recur2<<<256, 512, 0, stream>>>(wrec, b_iouh, b_Uh, hx, proj, hbuf, rhbuf, flags, out);
}

// Round 3
// 15741.739 us; speedup vs baseline: 1.1254x; 1.1254x over previous
//
#include <hip/hip_runtime.h>
#include <hip/hip_bf16.h>

typedef _Float16 half4v __attribute__((ext_vector_type(4)));
typedef _Float16 half8v __attribute__((ext_vector_type(8)));
typedef float f32x4 __attribute__((ext_vector_type(4)));

#define T_STEPS 256
#define BATCH 64
#define NHID 512
#define NINP 512
#define MROWS (T_STEPS * BATCH)          // 16384
#define KDIM (2 * NINP)                  // 1024
#define NOUT (2 * NHID + NHID)           // 1536

// ---------------------------------------------------------------- converts

__global__ __launch_bounds__(256) void k_convert_x(
    const float* __restrict__ inp, const float* __restrict__ sem,
    _Float16* __restrict__ xh) {
  int idx = blockIdx.x * 256 + threadIdx.x;
  const int G = MROWS * KDIM / 4;
  for (int g = idx; g < G; g += 2048 * 256) {
    int e = g * 4;
    int m = e >> 10, k = e & 1023;
    const float* src = (k < NINP) ? (inp + (size_t)m * NINP + k)
                                  : (sem + (size_t)m * NINP + (k - NINP));
    float4 v = *(const float4*)src;
    half4v o = { (_Float16)v.x, (_Float16)v.y, (_Float16)v.z, (_Float16)v.w };
    *(half4v*)(xh + (size_t)e) = o;
  }
}

// biasN folds BOTH the x-side and recurrent biases:
//   biasN[j]      = b_ioux[j] + b_iouh[j]        (j < 1024)
//   biasN[1024+i] = b_fx[i]   + b_Uh[i]
__global__ __launch_bounds__(256) void k_convert_w(
    const float* __restrict__ W_ioux, const float* __restrict__ W_fx,
    const float* __restrict__ b_ioux, const float* __restrict__ b_fx,
    const float* __restrict__ b_iouh, const float* __restrict__ b_Uh,
    _Float16* __restrict__ wbig, float* __restrict__ biasN) {
  int g = blockIdx.x * 256 + threadIdx.x;
  int e = g * 4;
  int n = e >> 10, k = e & 1023;
  const float* src = (n < 2 * NHID) ? (W_ioux + (size_t)n * KDIM + k)
                                    : (W_fx + (size_t)(n - 2 * NHID) * KDIM + k);
  float4 v = *(const float4*)src;
  half4v o = { (_Float16)v.x, (_Float16)v.y, (_Float16)v.z, (_Float16)v.w };
  *(half4v*)(wbig + (size_t)e) = o;
  if (g < NOUT)
    biasN[g] = (g < 2 * NHID) ? (b_ioux[g] + b_iouh[g])
                              : (b_fx[g - 2 * NHID] + b_Uh[g - 2 * NHID]);
}

__global__ __launch_bounds__(256) void k_convert_wrec(
    const float* __restrict__ W_iouh, const float* __restrict__ W_Uh,
    _Float16* __restrict__ wrec) {
  int g = blockIdx.x * 256 + threadIdx.x;
  int e = g * 4;
  const int NI = 2 * NHID * NHID;
  const float* src = (e < NI) ? (W_iouh + e) : (W_Uh + (e - NI));
  float4 v = *(const float4*)src;
  half4v o = { (_Float16)v.x, (_Float16)v.y, (_Float16)v.z, (_Float16)v.w };
  *(half4v*)(wrec + (size_t)e) = o;
}

// ---------------------------------------------------------------- GEMM

__device__ __forceinline__ void gload16(const void* g, void* l) {
  __builtin_amdgcn_global_load_lds(
      (const __attribute__((address_space(1))) unsigned int*)g,
      (__attribute__((address_space(3))) unsigned int*)l, 16, 0, 0);
}

__global__ __launch_bounds__(256) void gemm_bt(
    const _Float16* __restrict__ A, const _Float16* __restrict__ Bm,
    const float* __restrict__ biasN, float* __restrict__ C,
    int M, int N, int K) {
  __shared__ __align__(16) _Float16 As[128 * 32];
  __shared__ __align__(16) _Float16 Bs[128 * 32];
  const int tid = threadIdx.x;
  const int lane = tid & 63;
  const int w = tid >> 6;
  const int wr = w >> 1, wc = w & 1;
  const int nbm = M >> 7;
  const int bm = blockIdx.x % nbm, bn = blockIdx.x / nbm;
  const int m0 = bm << 7, n0 = bn << 7;
  const int lr = lane & 15, lh = lane >> 4;

  f32x4 acc[4][4] = {};

  for (int kk = 0; kk < K; kk += 32) {
#pragma unroll
    for (int c = 0; c < 2; ++c) {
      int L = (c * 256 + tid) * 16;
      int row = L >> 6, inrow = L & 63;
      gload16((const char*)A + ((size_t)(m0 + row) * K + kk) * 2 + inrow,
              (char*)As + L);
      gload16((const char*)Bm + ((size_t)(n0 + row) * K + kk) * 2 + inrow,
              (char*)Bs + L);
    }
    __syncthreads();
    half8v af[4], bf[4];
#pragma unroll
    for (int i = 0; i < 4; ++i)
      af[i] = *(const half8v*)&As[(wr * 64 + i * 16 + lr) * 32 + lh * 8];
#pragma unroll
    for (int i = 0; i < 4; ++i)
      bf[i] = *(const half8v*)&Bs[(wc * 64 + i * 16 + lr) * 32 + lh * 8];
#pragma unroll
    for (int i = 0; i < 4; ++i)
#pragma unroll
      for (int j = 0; j < 4; ++j)
        acc[i][j] = __builtin_amdgcn_mfma_f32_16x16x32_f16(af[i], bf[j], acc[i][j], 0, 0, 0);
    __syncthreads();
  }

#pragma unroll
  for (int i = 0; i < 4; ++i)
#pragma unroll
    for (int j = 0; j < 4; ++j) {
      int n = n0 + wc * 64 + j * 16 + lr;
      float bv = biasN[n];
#pragma unroll
      for (int q = 0; q < 4; ++q) {
        int m = m0 + wr * 64 + i * 16 + lh * 4 + q;
        C[(size_t)m * N + n] = acc[i][j][q] + bv;
      }
    }
}

// ---------------------------------------------------------------- recurrence
// 4 WGs/chain, 256 threads/WG, 1 WG/CU (launch_bounds(256,1) -> 512 VGPR budget).
// Thread (row=tid>>1, q=tid&1) owns z-row u, r-row 512+u, Uh-row u for its
// K-half. Weights pinned: 3*32 half8v = 384 VGPRs. No LDS. Per-chain flag
// region (256B), release-store producers, all-wave parallel polling.

__device__ __forceinline__ float dot8(half8v a, half8v b, float acc) {
  acc = __builtin_amdgcn_fdot2(__builtin_shufflevector(a, a, 0, 1),
                               __builtin_shufflevector(b, b, 0, 1), acc, false);
  acc = __builtin_amdgcn_fdot2(__builtin_shufflevector(a, a, 2, 3),
                               __builtin_shufflevector(b, b, 2, 3), acc, false);
  acc = __builtin_amdgcn_fdot2(__builtin_shufflevector(a, a, 4, 5),
                               __builtin_shufflevector(b, b, 4, 5), acc, false);
  acc = __builtin_amdgcn_fdot2(__builtin_shufflevector(a, a, 6, 7),
                               __builtin_shufflevector(b, b, 6, 7), acc, false);
  return acc;
}

__device__ __forceinline__ float sigm(float v) { return 1.f / (1.f + __expf(-v)); }

__global__ __launch_bounds__(256, 1) void recur3(
    const _Float16* __restrict__ Wrec, const float* __restrict__ hx,
    const float* __restrict__ proj, _Float16* __restrict__ hbuf,
    _Float16* __restrict__ rhbuf, int* __restrict__ flags,
    float* __restrict__ out) {
  const int bid = blockIdx.x;
  const int c = bid & 63, g = bid >> 6;     // 4 WGs of chain c on same XCD
  const int tid = threadIdx.x;
  const int lane = tid & 63;
  const int q = tid & 1, row = tid >> 1;    // row 0..127, K-half q
  const int u = g * 128 + row;
  const int jz = u, jr = 512 + u;

  int* hfl = flags + c * 64;                // ints [0..3] used
  int* rfl = flags + c * 64 + 8;            // ints [8..11] used

  const _Float16* WU = Wrec + (size_t)1024 * 512;

  // pin weights: 3 x 32 half8v = 384 VGPRs
  half8v wz[32], wr[32], wu[32];
#pragma unroll
  for (int i = 0; i < 32; ++i) {
    wz[i] = *(const half8v*)(Wrec + (size_t)jz * 512 + q * 256 + i * 8);
    wr[i] = *(const half8v*)(Wrec + (size_t)jr * 512 + q * 256 + i * 8);
    wu[i] = *(const half8v*)(WU  + (size_t)u  * 512 + q * 256 + i * 8);
  }

  float hmy = 0.f;
  if (q == 0) {
    hmy = hx[(size_t)c * 512 + u];
    hbuf[(size_t)c * 512 + u] = (_Float16)hmy;
  }
  __syncthreads();
  __threadfence();
  if (tid == 0)
    __hip_atomic_store(&hfl[g], 1, __ATOMIC_RELEASE, __HIP_MEMORY_SCOPE_AGENT);

  const _Float16* hsrc = hbuf + (size_t)c * 512 + q * 256;
  const _Float16* rsrc = rhbuf + (size_t)c * 512 + q * 256;

  for (int t = 0; t < T_STEPS; ++t) {
    // proj loads are flag-independent: issue before the spin
    const float* pb = proj + (size_t)(t * BATCH + c) * NOUT;
    float pz = 0.f, pr = 0.f, pf = 0.f;
    if (q == 0) { pz = pb[jz]; pr = pb[jr]; pf = pb[1024 + u]; }

    // ---- wait for h_t (4 flags, lanes 0-3 poll in parallel, per wave)
    {
      const int need = t + 1;
      int v = need;
      if (lane < 4)
        v = __hip_atomic_load(&hfl[lane], __ATOMIC_ACQUIRE, __HIP_MEMORY_SCOPE_AGENT);
      while (__any(v < need)) {
        __builtin_amdgcn_s_sleep(1);
        if (lane < 4)
          v = __hip_atomic_load(&hfl[lane], __ATOMIC_ACQUIRE, __HIP_MEMORY_SCOPE_AGENT);
      }
    }

    // ---- phase 1: z, r (K-half per lane, pair-reduce)
    float za0 = 0.f, za1 = 0.f, ra0 = 0.f, ra1 = 0.f;
#pragma unroll
    for (int i = 0; i < 32; i += 2) {
      half8v h0 = *(const half8v*)(hsrc + i * 8);
      half8v h1 = *(const half8v*)(hsrc + i * 8 + 8);
      za0 = dot8(wz[i], h0, za0);     ra0 = dot8(wr[i], h0, ra0);
      za1 = dot8(wz[i + 1], h1, za1); ra1 = dot8(wr[i + 1], h1, ra1);
    }
    float zs = za0 + za1, rs = ra0 + ra1;
    float za = zs + __shfl_xor(zs, 1);
    float ra = rs + __shfl_xor(rs, 1);

    float zk = 0.f;
    if (q == 0) {
      zk = sigm(za + pz);
      float rv = sigm(ra + pr);
      rhbuf[(size_t)c * 512 + u] = (_Float16)(rv * hmy);
    }
    __syncthreads();
    __threadfence();
    if (tid == 0)
      __hip_atomic_store(&rfl[g], t + 1, __ATOMIC_RELEASE, __HIP_MEMORY_SCOPE_AGENT);

    // ---- wait for full r*h
    {
      const int need = t + 1;
      int v = need;
      if (lane < 4)
        v = __hip_atomic_load(&rfl[lane], __ATOMIC_ACQUIRE, __HIP_MEMORY_SCOPE_AGENT);
      while (__any(v < need)) {
        __builtin_amdgcn_s_sleep(1);
        if (lane < 4)
          v = __hip_atomic_load(&rfl[lane], __ATOMIC_ACQUIRE, __HIP_MEMORY_SCOPE_AGENT);
      }
    }

    // ---- phase 2: htilde, h_new
    float ua0 = 0.f, ua1 = 0.f;
#pragma unroll
    for (int i = 0; i < 32; i += 2) {
      half8v r0 = *(const half8v*)(rsrc + i * 8);
      half8v r1 = *(const half8v*)(rsrc + i * 8 + 8);
      ua0 = dot8(wu[i], r0, ua0);
      ua1 = dot8(wu[i + 1], r1, ua1);
    }
    float us = ua0 + ua1;
    float ua = us + __shfl_xor(us, 1);

    if (q == 0) {
      float v = ua + pf;
      float e = __expf(-2.f * fabsf(v));
      float th = (1.f - e) / (1.f + e);
      th = (v < 0.f) ? -th : th;
      float hn = fmaf(zk, th - hmy, hmy);
      out[(size_t)(t * BATCH + c) * NHID + u] = hn;
      hmy = hn;
      hbuf[(size_t)c * 512 + u] = (_Float16)hn;
    }
    __syncthreads();
    __threadfence();
    if (tid == 0)
      __hip_atomic_store(&hfl[g], t + 2, __ATOMIC_RELEASE, __HIP_MEMORY_SCOPE_AGENT);
  }

  if (q == 0)
    out[(size_t)T_STEPS * BATCH * NHID + (size_t)c * NHID + u] = hmy;
}

// ---------------------------------------------------------------- launcher

extern "C" void kernel_launch(void* const* d_in, const int* in_sizes, int n_in,
                              void* d_out, int out_size, void* d_ws, size_t ws_size,
                              hipStream_t stream) {
  const float* inputs = (const float*)d_in[0];
  const float* sememe = (const float*)d_in[1];
  const float* hx     = (const float*)d_in[2];
  const float* W_ioux = (const float*)d_in[3];
  const float* b_ioux = (const float*)d_in[4];
  const float* W_iouh = (const float*)d_in[5];
  const float* b_iouh = (const float*)d_in[6];
  const float* W_fx   = (const float*)d_in[7];
  const float* b_fx   = (const float*)d_in[8];
  const float* W_Uh   = (const float*)d_in[9];
  const float* b_Uh   = (const float*)d_in[10];
  float* out = (float*)d_out;

  char* ws = (char*)d_ws;
  _Float16* xh = (_Float16*)ws;   ws += (size_t)MROWS * KDIM * 2;
  _Float16* wbig = (_Float16*)ws; ws += (size_t)NOUT * KDIM * 2;
  float* biasN = (float*)ws;      ws += (size_t)NOUT * 4;
  _Float16* wrec = (_Float16*)ws; ws += (size_t)(3 * NHID * NHID) * 2;
  float* proj = (float*)ws;       ws += (size_t)MROWS * NOUT * 4;
  _Float16* hbuf = (_Float16*)ws; ws += (size_t)BATCH * NHID * 2;
  _Float16* rhbuf = (_Float16*)ws; ws += (size_t)BATCH * NHID * 2;
  int* flags = (int*)ws;          ws += (size_t)BATCH * 64 * 4;   // 256B/chain

  hipMemsetAsync(flags, 0, (size_t)BATCH * 64 * 4, stream);
  k_convert_x<<<2048, 256, 0, stream>>>(inputs, sememe, xh);
  k_convert_w<<<(NOUT * KDIM / 4) / 256, 256, 0, stream>>>(
      W_ioux, W_fx, b_ioux, b_fx, b_iouh, b_Uh, wbig, biasN);
  k_convert_wrec<<<(3 * NHID * NHID / 4) / 256, 256, 0, stream>>>(W_iouh, W_Uh, wrec);
  gemm_bt<<<(MROWS / 128) * (NOUT / 128), 256, 0, stream>>>(
      xh, wbig, biasN, proj, MROWS, NOUT, KDIM);
  recur3<<<256, 256, 0, stream>>>(wrec, hx, proj, hbuf, rhbuf, flags, out);
}

// Round 4
// 2403.116 us; speedup vs baseline: 7.3720x; 6.5506x over previous
//
#include <hip/hip_runtime.h>
#include <hip/hip_bf16.h>

typedef _Float16 half4v __attribute__((ext_vector_type(4)));
typedef _Float16 half8v __attribute__((ext_vector_type(8)));
typedef float f32x4 __attribute__((ext_vector_type(4)));

#define T_STEPS 256
#define BATCH 64
#define NHID 512
#define NINP 512
#define MROWS (T_STEPS * BATCH)          // 16384
#define KDIM (2 * NINP)                  // 1024
#define NOUT (2 * NHID + NHID)           // 1536

// ---------------------------------------------------------------- converts

__global__ __launch_bounds__(256) void k_convert_x(
    const float* __restrict__ inp, const float* __restrict__ sem,
    _Float16* __restrict__ xh) {
  int idx = blockIdx.x * 256 + threadIdx.x;
  const int G = MROWS * KDIM / 4;
  for (int g = idx; g < G; g += 2048 * 256) {
    int e = g * 4;
    int m = e >> 10, k = e & 1023;
    const float* src = (k < NINP) ? (inp + (size_t)m * NINP + k)
                                  : (sem + (size_t)m * NINP + (k - NINP));
    float4 v = *(const float4*)src;
    half4v o = { (_Float16)v.x, (_Float16)v.y, (_Float16)v.z, (_Float16)v.w };
    *(half4v*)(xh + (size_t)e) = o;
  }
}

// biasN folds BOTH the x-side and recurrent biases.
__global__ __launch_bounds__(256) void k_convert_w(
    const float* __restrict__ W_ioux, const float* __restrict__ W_fx,
    const float* __restrict__ b_ioux, const float* __restrict__ b_fx,
    const float* __restrict__ b_iouh, const float* __restrict__ b_Uh,
    _Float16* __restrict__ wbig, float* __restrict__ biasN) {
  int g = blockIdx.x * 256 + threadIdx.x;
  int e = g * 4;
  int n = e >> 10, k = e & 1023;
  const float* src = (n < 2 * NHID) ? (W_ioux + (size_t)n * KDIM + k)
                                    : (W_fx + (size_t)(n - 2 * NHID) * KDIM + k);
  float4 v = *(const float4*)src;
  half4v o = { (_Float16)v.x, (_Float16)v.y, (_Float16)v.z, (_Float16)v.w };
  *(half4v*)(wbig + (size_t)e) = o;
  if (g < NOUT)
    biasN[g] = (g < 2 * NHID) ? (b_ioux[g] + b_iouh[g])
                              : (b_fx[g - 2 * NHID] + b_Uh[g - 2 * NHID]);
}

__global__ __launch_bounds__(256) void k_convert_wrec(
    const float* __restrict__ W_iouh, const float* __restrict__ W_Uh,
    _Float16* __restrict__ wrec) {
  int g = blockIdx.x * 256 + threadIdx.x;
  int e = g * 4;
  const int NI = 2 * NHID * NHID;
  const float* src = (e < NI) ? (W_iouh + e) : (W_Uh + (e - NI));
  float4 v = *(const float4*)src;
  half4v o = { (_Float16)v.x, (_Float16)v.y, (_Float16)v.z, (_Float16)v.w };
  *(half4v*)(wrec + (size_t)e) = o;
}

// ---------------------------------------------------------------- GEMM

__device__ __forceinline__ void gload16(const void* g, void* l) {
  __builtin_amdgcn_global_load_lds(
      (const __attribute__((address_space(1))) unsigned int*)g,
      (__attribute__((address_space(3))) unsigned int*)l, 16, 0, 0);
}

__global__ __launch_bounds__(256) void gemm_bt(
    const _Float16* __restrict__ A, const _Float16* __restrict__ Bm,
    const float* __restrict__ biasN, float* __restrict__ C,
    int M, int N, int K) {
  __shared__ __align__(16) _Float16 As[128 * 32];
  __shared__ __align__(16) _Float16 Bs[128 * 32];
  const int tid = threadIdx.x;
  const int lane = tid & 63;
  const int w = tid >> 6;
  const int wr = w >> 1, wc = w & 1;
  const int nbm = M >> 7;
  const int bm = blockIdx.x % nbm, bn = blockIdx.x / nbm;
  const int m0 = bm << 7, n0 = bn << 7;
  const int lr = lane & 15, lh = lane >> 4;

  f32x4 acc[4][4] = {};

  for (int kk = 0; kk < K; kk += 32) {
#pragma unroll
    for (int c = 0; c < 2; ++c) {
      int L = (c * 256 + tid) * 16;
      int row = L >> 6, inrow = L & 63;
      gload16((const char*)A + ((size_t)(m0 + row) * K + kk) * 2 + inrow,
              (char*)As + L);
      gload16((const char*)Bm + ((size_t)(n0 + row) * K + kk) * 2 + inrow,
              (char*)Bs + L);
    }
    __syncthreads();
    half8v af[4], bf[4];
#pragma unroll
    for (int i = 0; i < 4; ++i)
      af[i] = *(const half8v*)&As[(wr * 64 + i * 16 + lr) * 32 + lh * 8];
#pragma unroll
    for (int i = 0; i < 4; ++i)
      bf[i] = *(const half8v*)&Bs[(wc * 64 + i * 16 + lr) * 32 + lh * 8];
#pragma unroll
    for (int i = 0; i < 4; ++i)
#pragma unroll
      for (int j = 0; j < 4; ++j)
        acc[i][j] = __builtin_amdgcn_mfma_f32_16x16x32_f16(af[i], bf[j], acc[i][j], 0, 0, 0);
    __syncthreads();
  }

#pragma unroll
  for (int i = 0; i < 4; ++i)
#pragma unroll
    for (int j = 0; j < 4; ++j) {
      int n = n0 + wc * 64 + j * 16 + lr;
      float bv = biasN[n];
#pragma unroll
      for (int q = 0; q < 4; ++q) {
        int m = m0 + wr * 64 + i * 16 + lh * 4 + q;
        C[(size_t)m * N + n] = acc[i][j][q] + bv;
      }
    }
}

// ---------------------------------------------------------------- recurrence
// 4 WGs/chain, 256 threads (4 waves). Weights stream from warm per-XCD L2
// (never invalidated: spins use RELAXED atomics; cross-WG data moves via
// sc1/LLC relaxed-atomic stores+loads; no fences, no acquire, no wbl2).
// Lane map: oct = row-within-8, okt = K-eighth; 128B contiguous weight
// segments per row, LDS h reads are 8-addr broadcasts (conflict-free).

__device__ __forceinline__ float dot8(half8v a, half8v b, float acc) {
  acc = __builtin_amdgcn_fdot2(__builtin_shufflevector(a, a, 0, 1),
                               __builtin_shufflevector(b, b, 0, 1), acc, false);
  acc = __builtin_amdgcn_fdot2(__builtin_shufflevector(a, a, 2, 3),
                               __builtin_shufflevector(b, b, 2, 3), acc, false);
  acc = __builtin_amdgcn_fdot2(__builtin_shufflevector(a, a, 4, 5),
                               __builtin_shufflevector(b, b, 4, 5), acc, false);
  acc = __builtin_amdgcn_fdot2(__builtin_shufflevector(a, a, 6, 7),
                               __builtin_shufflevector(b, b, 6, 7), acc, false);
  return acc;
}

__device__ __forceinline__ float sigm(float v) { return 1.f / (1.f + __expf(-v)); }

__device__ __forceinline__ void wait4(int* f, int need, int lane) {
  int v = need;
  if (lane < 4)
    v = __hip_atomic_load(&f[lane], __ATOMIC_RELAXED, __HIP_MEMORY_SCOPE_AGENT);
  while (__any(v < need)) {
    __builtin_amdgcn_s_sleep(2);
    if (lane < 4)
      v = __hip_atomic_load(&f[lane], __ATOMIC_RELAXED, __HIP_MEMORY_SCOPE_AGENT);
  }
}

__device__ __forceinline__ void st16(unsigned short* p, _Float16 x) {
  __hip_atomic_store(p, __builtin_bit_cast(unsigned short, x),
                     __ATOMIC_RELAXED, __HIP_MEMORY_SCOPE_AGENT);
}

__global__ __launch_bounds__(256, 1) void recur4(
    const _Float16* __restrict__ Wrec, const float* __restrict__ hx,
    const float* __restrict__ proj, unsigned short* __restrict__ hbuf,
    unsigned short* __restrict__ rhbuf, int* __restrict__ flags,
    float* __restrict__ out) {
  __shared__ __align__(16) _Float16 hh[NHID];
  __shared__ __align__(16) _Float16 rr[NHID];
  __shared__ float hout[128];

  const int bid = blockIdx.x;
  const int c = bid & 63, g = bid >> 6;    // 4 WGs of chain c, same XCD (heuristic)
  const int tid = threadIdx.x;
  const int lane = tid & 63;
  const int w = tid >> 6;
  const int oct = lane >> 3, okt = lane & 7;

  int* hfl = flags + c * 64;               // [0..3]
  int* rfl = flags + c * 64 + 8;           // [8..11]
  const _Float16* WU = Wrec + (size_t)1024 * 512;
  unsigned short* hbC = hbuf + (size_t)c * 512;
  unsigned short* rbC = rhbuf + (size_t)c * 512;

  // okt==0 threads own 4 hidden rows each: u = g*128 + p*32 + w*8 + oct
  float hmy[4] = {0, 0, 0, 0}, zk[4] = {0, 0, 0, 0};
  if (okt == 0) {
#pragma unroll
    for (int p = 0; p < 4; ++p) {
      int u = g * 128 + p * 32 + w * 8 + oct;
      hmy[p] = hx[(size_t)c * 512 + u];
      st16(&hbC[u], (_Float16)hmy[p]);
    }
  }
  __syncthreads();                         // drains vmcnt across WG
  if (tid == 0)
    __hip_atomic_store(&hfl[g], 1, __ATOMIC_RELAXED, __HIP_MEMORY_SCOPE_AGENT);

  for (int t = 0; t < T_STEPS; ++t) {
    // flag-independent proj loads: issue before the spin
    const float* pb = proj + (size_t)(t * BATCH + c) * NOUT;
    float pzv[4] = {0, 0, 0, 0}, prv[4] = {0, 0, 0, 0}, pfv[4] = {0, 0, 0, 0};
    if (okt == 0) {
#pragma unroll
      for (int p = 0; p < 4; ++p) {
        int k = g * 128 + p * 32 + w * 8 + oct;
        pzv[p] = pb[k];
        prv[p] = pb[512 + k];
        pfv[p] = pb[1024 + k];
      }
    }

    // ---- wait h_t, stage into LDS via sc1 dword loads
    wait4(hfl, t + 1, lane);
    asm volatile("" ::: "memory");
    {
      unsigned v = __hip_atomic_load((const unsigned*)hbC + tid,
                                     __ATOMIC_RELAXED, __HIP_MEMORY_SCOPE_AGENT);
      ((unsigned*)hh)[tid] = v;
    }
    __syncthreads();

    // ---- phase 1: z rows (idx<128) and r rows (idx>=128)
#pragma unroll 2
    for (int p = 0; p < 8; ++p) {
      int idx = p * 32 + w * 8 + oct;      // 0..255
      int j = (idx < 128) ? (g * 128 + idx) : (512 + g * 128 + (idx - 128));
      const _Float16* wp = Wrec + (size_t)j * 512 + okt * 8;
      float acc = 0.f;
#pragma unroll
      for (int it = 0; it < 8; ++it) {
        half8v wv = *(const half8v*)(wp + it * 64);
        half8v hv = *(const half8v*)(hh + it * 64 + okt * 8);
        acc = dot8(wv, hv, acc);
      }
      acc += __shfl_xor(acc, 1);
      acc += __shfl_xor(acc, 2);
      acc += __shfl_xor(acc, 4);
      if (okt == 0) {
        if (idx < 128) {
          zk[p] = sigm(acc + pzv[p]);
        } else {
          float rv = sigm(acc + prv[p - 4]);
          st16(&rbC[g * 128 + (idx - 128)], (_Float16)(rv * hmy[p - 4]));
        }
      }
    }
    __syncthreads();                       // drains vmcnt
    if (tid == 0)
      __hip_atomic_store(&rfl[g], t + 1, __ATOMIC_RELAXED, __HIP_MEMORY_SCOPE_AGENT);

    // ---- wait r*h, stage into LDS
    wait4(rfl, t + 1, lane);
    asm volatile("" ::: "memory");
    {
      unsigned v = __hip_atomic_load((const unsigned*)rbC + tid,
                                     __ATOMIC_RELAXED, __HIP_MEMORY_SCOPE_AGENT);
      ((unsigned*)rr)[tid] = v;
    }
    __syncthreads();

    // ---- phase 2: htilde, h update
#pragma unroll 2
    for (int p = 0; p < 4; ++p) {
      int idx = p * 32 + w * 8 + oct;
      int u = g * 128 + idx;
      const _Float16* wp = WU + (size_t)u * 512 + okt * 8;
      float acc = 0.f;
#pragma unroll
      for (int it = 0; it < 8; ++it) {
        half8v wv = *(const half8v*)(wp + it * 64);
        half8v rv = *(const half8v*)(rr + it * 64 + okt * 8);
        acc = dot8(wv, rv, acc);
      }
      acc += __shfl_xor(acc, 1);
      acc += __shfl_xor(acc, 2);
      acc += __shfl_xor(acc, 4);
      if (okt == 0) {
        float v = acc + pfv[p];
        float e = __expf(-2.f * fabsf(v));
        float th = (1.f - e) / (1.f + e);
        th = (v < 0.f) ? -th : th;
        float hn = fmaf(zk[p], th - hmy[p], hmy[p]);
        hmy[p] = hn;
        hout[idx] = hn;
        st16(&hbC[u], (_Float16)hn);
      }
    }
    __syncthreads();                       // drains vmcnt + lds
    if (tid == 0)
      __hip_atomic_store(&hfl[g], t + 2, __ATOMIC_RELAXED, __HIP_MEMORY_SCOPE_AGENT);

    // coalesced out write (off the critical path, after flag post)
    if (tid < 128)
      out[(size_t)(t * BATCH + c) * NHID + g * 128 + tid] = hout[tid];
  }

  if (okt == 0) {
#pragma unroll
    for (int p = 0; p < 4; ++p) {
      int u = g * 128 + p * 32 + w * 8 + oct;
      out[(size_t)T_STEPS * BATCH * NHID + (size_t)c * NHID + u] = hmy[p];
    }
  }
}

// ---------------------------------------------------------------- launcher

extern "C" void kernel_launch(void* const* d_in, const int* in_sizes, int n_in,
                              void* d_out, int out_size, void* d_ws, size_t ws_size,
                              hipStream_t stream) {
  const float* inputs = (const float*)d_in[0];
  const float* sememe = (const float*)d_in[1];
  const float* hx     = (const float*)d_in[2];
  const float* W_ioux = (const float*)d_in[3];
  const float* b_ioux = (const float*)d_in[4];
  const float* W_iouh = (const float*)d_in[5];
  const float* b_iouh = (const float*)d_in[6];
  const float* W_fx   = (const float*)d_in[7];
  const float* b_fx   = (const float*)d_in[8];
  const float* W_Uh   = (const float*)d_in[9];
  const float* b_Uh   = (const float*)d_in[10];
  float* out = (float*)d_out;

  char* ws = (char*)d_ws;
  _Float16* xh = (_Float16*)ws;   ws += (size_t)MROWS * KDIM * 2;
  _Float16* wbig = (_Float16*)ws; ws += (size_t)NOUT * KDIM * 2;
  float* biasN = (float*)ws;      ws += (size_t)NOUT * 4;
  _Float16* wrec = (_Float16*)ws; ws += (size_t)(3 * NHID * NHID) * 2;
  float* proj = (float*)ws;       ws += (size_t)MROWS * NOUT * 4;
  unsigned short* hbuf = (unsigned short*)ws;  ws += (size_t)BATCH * NHID * 2;
  unsigned short* rhbuf = (unsigned short*)ws; ws += (size_t)BATCH * NHID * 2;
  int* flags = (int*)ws;          ws += (size_t)BATCH * 64 * 4;

  hipMemsetAsync(flags, 0, (size_t)BATCH * 64 * 4, stream);
  k_convert_x<<<2048, 256, 0, stream>>>(inputs, sememe, xh);
  k_convert_w<<<(NOUT * KDIM / 4) / 256, 256, 0, stream>>>(
      W_ioux, W_fx, b_ioux, b_fx, b_iouh, b_Uh, wbig, biasN);
  k_convert_wrec<<<(3 * NHID * NHID / 4) / 256, 256, 0, stream>>>(W_iouh, W_Uh, wrec);
  gemm_bt<<<(MROWS / 128) * (NOUT / 128), 256, 0, stream>>>(
      xh, wbig, biasN, proj, MROWS, NOUT, KDIM);
  recur4<<<256, 256, 0, stream>>>(wrec, hx, proj, hbuf, rhbuf, flags, out);
}